// Round 6
// baseline (170.186 us; speedup 1.0000x reference)
//
#include <hip/hip_runtime.h>
#include <hip/hip_bf16.h>

// Gaussian-kernel regression, fused flash-attention style.
// K_main: single-barrier double-buffered K-loop; S=(KA2C*yt)@x via MFMA (K=128),
//   e = sa + yn (f32), g=exp2(e); P C-layout -> B-operand via lane^32 shuffle
//   (no LDS round-trip); PV full-rate 32x32x16. LDS = 2x32KB = 64KB, 2 blocks/CU.
// K_prep: blocks 0..63: yt GEMM -> scaled perm + yn(f32); 64..191: V perm
// K_fin : reduce splits (col-split grid), normalize, transpose, store

#define LOG2E 1.44269504088896340736f
#define KNEG (-(1.0f/256.0f)*LOG2E)
#define KA2C (2.0f*(1.0f/256.0f)*LOG2E)

typedef __attribute__((ext_vector_type(4)))  float f32x4;
typedef __attribute__((ext_vector_type(16))) float f32x16;
typedef __attribute__((ext_vector_type(8)))  short bf16x8;

__device__ __forceinline__ unsigned short f2bf(float f) {
  unsigned u = __builtin_bit_cast(unsigned, f);
  u = (u + 0x7fffu + ((u >> 16) & 1u)) >> 16;  // RNE; inputs finite
  return (unsigned short)u;
}
__device__ __forceinline__ unsigned pk2bf(float a, float b) {
  __hip_bfloat162 h = __float22bfloat162_rn(float2{a, b});  // v_cvt_pk_bf16_f32
  unsigned u;
  __builtin_memcpy(&u, &h, 4);
  return u;
}
__device__ __forceinline__ bf16x8 pack8(float4 p0, float4 p1) {
  uint4 u;
  u.x = pk2bf(p0.x, p0.y); u.y = pk2bf(p0.z, p0.w);
  u.z = pk2bf(p1.x, p1.y); u.w = pk2bf(p1.z, p1.w);
  return __builtin_bit_cast(bf16x8, u);
}
__device__ __forceinline__ float fast_exp2(float x) {
#if __has_builtin(__builtin_amdgcn_exp2f)
  return __builtin_amdgcn_exp2f(x);
#else
  return exp2f(x);
#endif
}
__device__ __forceinline__ void gl2lds16(const void* g, void* l) {
  __builtin_amdgcn_global_load_lds((const __attribute__((address_space(1))) unsigned int*)g,
                                   (__attribute__((address_space(3))) unsigned int*)l, 16, 0, 0);
}
__device__ __forceinline__ f32x16 mfma_32x32x16(bf16x8 a, bf16x8 b, f32x16 c) {
  return __builtin_amdgcn_mfma_f32_32x32x16_bf16(a, b, c, 0, 0, 0);
}

#define T_STRIDE 32768   // per-tile bytes: 16 yt chunks + 16 V chunks (1 KB each)
#define V_OFF    16384

// ---------------- K_prep ----------------
// blocks 0..63  : yt part, 128 rows/block (4 waves x 32 rows)
// blocks 64..191: V part, 64 rows/block
__global__ __launch_bounds__(256) void k_prep(const float* __restrict__ y,
                                              const float* __restrict__ R,
                                              const float* __restrict__ t,
                                              const float* __restrict__ X,
                                              unsigned short* __restrict__ ctp,
                                              float* __restrict__ ynp) {
  __shared__ union {
    unsigned short ytt[128 * 132];
    float xt[65 * 132];
  } sm;
  const int tid = threadIdx.x;

  if (blockIdx.x < 64) {
    // ------- yt = y@R^T + t; store KA2C*yt (bf16 perm) + yn (f32) -------
    const int wv = tid >> 6, ln = tid & 63;
    const int l = ln & 31, h = ln >> 5;
    const int B = blockIdx.x;
    const int rw = B * 128 + wv * 32;

    bf16x8 af[8];  // A-frag: y[rw+l][kc*16+8h+0..7]
    {
      int row = rw + l; if (row > 8190) row = 8190;
      const float* yr = y + (size_t)row * 128;
#pragma unroll
      for (int kc = 0; kc < 8; ++kc) {
        float4 p0 = *(const float4*)(yr + kc*16 + 8*h);
        float4 p1 = *(const float4*)(yr + kc*16 + 8*h + 4);
        af[kc] = pack8(p0, p1);
      }
    }
    f32x16 acc[4];
#pragma unroll
    for (int cc=0; cc<4; ++cc)
#pragma unroll
      for (int i=0;i<16;++i) acc[cc][i] = 0.f;
#pragma unroll
    for (int cc=0; cc<4; ++cc) {
      const float* Rr = R + (size_t)(cc*32 + l) * 128;  // B-frag: R^T[k][c] = R[c][k]
#pragma unroll
      for (int kc=0; kc<8; ++kc) {
        float4 p0 = *(const float4*)(Rr + kc*16 + 8*h);
        float4 p1 = *(const float4*)(Rr + kc*16 + 8*h + 4);
        acc[cc] = mfma_32x32x16(af[kc], pack8(p0, p1), acc[cc]);
      }
    }
    // D: lane holds yt[rw + (r&3)+8*(r>>2)+4h][cc*32 + l]
    float tv0 = t[l], tv1 = t[32+l], tv2 = t[64+l], tv3 = t[96+l];
    float v0[16], v1[16], v2[16], v3[16], ssq[16];
#pragma unroll
    for (int r=0;r<16;++r) {
      v0[r]=acc[0][r]+tv0; v1[r]=acc[1][r]+tv1; v2[r]=acc[2][r]+tv2; v3[r]=acc[3][r]+tv3;
      ssq[r] = v0[r]*v0[r] + v1[r]*v1[r] + v2[r]*v2[r] + v3[r]*v3[r];
    }
#pragma unroll
    for (int off=1; off<32; off<<=1)
#pragma unroll
      for (int r=0;r<16;++r) ssq[r] += __shfl_xor(ssq[r], off, 64);
    if (l < 16) {
      int r = l;
      int grow = rw + (r&3) + 8*(r>>2) + 4*h;
      ynp[grow] = (grow >= 8191) ? -1.0e30f : KNEG * ssq[r];  // pad j: g=0
    }
    // transpose scaled yt via LDS
#pragma unroll
    for (int r=0;r<16;++r) {
      int rloc = wv*32 + (r&3) + 8*(r>>2) + 4*h;
      sm.ytt[rloc*132 +   0 + l] = f2bf(KA2C * v0[r]);
      sm.ytt[rloc*132 +  32 + l] = f2bf(KA2C * v1[r]);
      sm.ytt[rloc*132 +  64 + l] = f2bf(KA2C * v2[r]);
      sm.ytt[rloc*132 +  96 + l] = f2bf(KA2C * v3[r]);
    }
    __syncthreads();
    // perm: [T][jc(2)][kc(8)][lane(64)][8 bf16]; lane ln -> tile-row jc*32+l, k = kc*16+8h
    const int Tt = B*2 + (wv>>1);
    const int jcw = wv & 1;
    char* base = (char*)ctp + (size_t)Tt*T_STRIDE;
#pragma unroll
    for (int kc=0;kc<8;++kc) {
      const unsigned short* s = &sm.ytt[(wv*32 + l)*132 + kc*16 + 8*h];
      uint2 a = *(const uint2*)(s);
      uint2 b = *(const uint2*)(s + 4);
      uint4 o; o.x=a.x; o.y=a.y; o.z=b.x; o.w=b.y;
      *(uint4*)(base + (jcw*8 + kc)*1024 + ln*16) = o;
    }
  } else {
    // ------- V = X[1:] transposed perm -------
    const int T = blockIdx.x - 64;
    const int jt = T * 64;
    {
      int rr = tid >> 2, q4 = tid & 3;
      int row = jt + rr; if (row > 8191) row = 8191;
      const float* src = X + (size_t)row*128 + q4*32;
      float* dst = &sm.xt[rr*132 + q4*32];
#pragma unroll
      for (int i=0;i<8;++i) *(float4*)(dst + i*4) = *(const float4*)(src + i*4);
      if (tid < 4) {
        int row2 = jt + 64; if (row2 > 8191) row2 = 8191;  // clamp (pad j has g=0)
        const float* s2 = X + (size_t)row2*128 + tid*32;
        float* d2 = &sm.xt[64*132 + tid*32];
#pragma unroll
        for (int i=0;i<8;++i) *(float4*)(d2 + i*4) = *(const float4*)(s2 + i*4);
      }
    }
    __syncthreads();
    // [T][jc16(4)][cc(4)][lane(64)][8 bf16]: lane -> X1[jc16*16+8h+i][cc*32+l]
    char* base = (char*)ctp + (size_t)T*T_STRIDE + V_OFF;
#pragma unroll
    for (int it=0; it<4; ++it) {
      int E = tid + it*256;
      int lp = E & 63, grp = E >> 6;
      int cc = grp & 3, jc16 = grp >> 2;
      int jb = jc16*16 + 8*(lp>>5);
      int c  = cc*32 + (lp & 31);
      uint4 o;
      o.x = pk2bf(sm.xt[(jb+1)*132 + c], sm.xt[(jb+2)*132 + c]);
      o.y = pk2bf(sm.xt[(jb+3)*132 + c], sm.xt[(jb+4)*132 + c]);
      o.z = pk2bf(sm.xt[(jb+5)*132 + c], sm.xt[(jb+6)*132 + c]);
      o.w = pk2bf(sm.xt[(jb+7)*132 + c], sm.xt[(jb+8)*132 + c]);
      *(uint4*)(base + E*16) = o;
    }
  }
}

// ---------------- K_main ----------------
// grid (64, js=8); block 256 = 4 waves x 32 query rows (BM=128); 2 blocks/CU.
// Single barrier per tile; stage T+1 into the other buffer right after it.
__global__ __launch_bounds__(256, 2) void k_main(
    const float* __restrict__ X,
    const unsigned short* __restrict__ ctp,
    const float* __restrict__ ynp,
    float* __restrict__ accp,
    float* __restrict__ rsp,
    int js) {
  __shared__ unsigned short stg[2][T_STRIDE/2];   // 2 x 32 KB = 64 KB
  const int tid = threadIdx.x;
  const int wv = tid >> 6, ln = tid & 63;
  const int l = ln & 31, h = ln >> 5;
  const int row = blockIdx.x*128 + wv*32 + l;  // query row, always < 8192

  bf16x8 qf[8];  // Q as B-operand: x[row][k = kc*16+8h+0..7]
  {
    const float* xr = X + (size_t)row * 128;
#pragma unroll
    for (int kc=0;kc<8;++kc) {
      float4 p0 = *(const float4*)(xr + kc*16 + 8*h);
      float4 p1 = *(const float4*)(xr + kc*16 + 8*h + 4);
      qf[kc] = pack8(p0, p1);
    }
  }
  f32x16 acc[4];
#pragma unroll
  for (int cc=0;cc<4;++cc)
#pragma unroll
    for (int i=0;i<16;++i) acc[cc][i]=0.f;
  float rs = 0.f;
  const int sp = blockIdx.y;
  const int Tbeg = (sp * 128) / js;
  const int Tend = ((sp + 1) * 128) / js;

  // stage first tile into buffer 0 (8 chunks per wave)
  {
    const char* cb = (const char*)ctp + (size_t)Tbeg*T_STRIDE;
#pragma unroll
    for (int i=0;i<8;++i) {
      int c = wv + 4*i;
      gl2lds16(cb + c*1024 + ln*16, (char*)stg[0] + c*1024);
    }
  }
  int cur = 0;
  for (int T = Tbeg; T < Tend; ++T) {
    __syncthreads();   // vmcnt drain -> stg[cur] ready; all prior reads of stg[cur^1] done
    if (T + 1 < Tend) {
      const char* cb = (const char*)ctp + (size_t)(T+1)*T_STRIDE;
#pragma unroll
      for (int i=0;i<8;++i) {
        int c = wv + 4*i;
        gl2lds16(cb + c*1024 + ln*16, (char*)stg[cur^1] + c*1024);
      }
    }
    const char* yb = (const char*)stg[cur];
    const char* vb = (const char*)stg[cur] + V_OFF;
    // yn broadcast loads (L1-hot 64 KB array)
    f32x4 yv[2][4];
#pragma unroll
    for (int jc=0;jc<2;++jc)
#pragma unroll
      for (int rg=0;rg<4;++rg)
        yv[jc][rg] = *(const f32x4*)(ynp + T*64 + jc*32 + 8*rg + 4*h);
    // S: two independent 8-MFMA chains
    f32x16 sa[2];
#pragma unroll
    for (int jc=0;jc<2;++jc) {
#pragma unroll
      for (int i=0;i<16;++i) sa[jc][i]=0.f;
#pragma unroll
      for (int kc=0;kc<8;++kc) {
        bf16x8 a = *(const bf16x8*)(yb + (jc*8+kc)*1024 + ln*16);
        sa[jc] = mfma_32x32x16(a, qf[kc], sa[jc]);
      }
    }
    // exp + shuffle-transpose P + PV
#pragma unroll
    for (int jc=0;jc<2;++jc) {
      float gg[16];
#pragma unroll
      for (int rg=0;rg<4;++rg) {
#pragma unroll
        for (int i=0;i<4;++i) {
          float g = fast_exp2(sa[jc][rg*4+i] + yv[jc][rg][i]);
          gg[rg*4+i] = g;
          rs += g;
        }
      }
#pragma unroll
      for (int b=0;b<2;++b) {
        // pb elem e at lane(l,h) = gg[8b+4h+(e&3)] from lane(l, e>>2)
        unsigned own0 = pk2bf(gg[8*b+4*h+0], gg[8*b+4*h+1]);
        unsigned own1 = pk2bf(gg[8*b+4*h+2], gg[8*b+4*h+3]);
        unsigned snd0 = pk2bf(gg[8*b+4-4*h+0], gg[8*b+4-4*h+1]);
        unsigned snd1 = pk2bf(gg[8*b+4-4*h+2], gg[8*b+4-4*h+3]);
        unsigned rcv0 = (unsigned)__shfl_xor((int)snd0, 32, 64);
        unsigned rcv1 = (unsigned)__shfl_xor((int)snd1, 32, 64);
        uint4 u;
        u.x = h ? rcv0 : own0;
        u.y = h ? rcv1 : own1;
        u.z = h ? own0 : rcv0;
        u.w = h ? own1 : rcv1;
        bf16x8 pb = __builtin_bit_cast(bf16x8, u);
        int jc16 = jc*2 + b;
#pragma unroll
        for (int cc=0;cc<4;++cc) {
          bf16x8 a2 = *(const bf16x8*)(vb + (jc16*4+cc)*1024 + ln*16);
          acc[cc] = mfma_32x32x16(a2, pb, acc[cc]);
        }
      }
    }
    cur ^= 1;
  }
  rs += __shfl_xor(rs, 32, 64);
  if (h == 0) rsp[(size_t)sp*8192 + row] = rs;
  // acc^T: lane holds out^T[c = cc*32+(r&3)+8(r>>2)+4h][m = row]; store [sp][c][row]
#pragma unroll
  for (int cc=0;cc<4;++cc)
#pragma unroll
    for (int r=0;r<16;++r) {
      int c = cc*32 + (r&3) + 8*(r>>2) + 4*h;
      accp[((size_t)sp*128 + c)*8192 + row] = acc[cc][r];
    }
}

// ---------------- K_fin: col-split coalesced reduce + normalize + transpose ----------------
// grid (128, 2); block 256. Block: 64 rows x 64 cols.
__global__ __launch_bounds__(256) void k_fin(const float* __restrict__ accp,
                                             const float* __restrict__ rsp,
                                             float* __restrict__ out,
                                             int js) {
  __shared__ float tr[64*68];
  __shared__ float rinv[64];
  const int tid = threadIdx.x;
  const int r0 = blockIdx.x * 64;
  const int c0 = blockIdx.y * 64;
  if (tid < 64) {
    float s = 0.f;
    for (int sp=0; sp<js; ++sp) s += rsp[(size_t)sp*8192 + r0 + tid];
    rinv[tid] = 1.f / s;
  }
  const int rq = tid & 15, cg = tid >> 4;   // rows rq*4..+3, cols c0+cg*4..+3
  float v[4][4];
#pragma unroll
  for (int cc=0;cc<4;++cc)
#pragma unroll
    for (int k=0;k<4;++k) v[cc][k]=0.f;
  for (int sp=0; sp<js; ++sp) {
    const float* base = accp + ((size_t)sp*128 + c0 + cg*4)*8192 + r0 + rq*4;
#pragma unroll
    for (int cc=0; cc<4; ++cc) {
      float4 p = *(const float4*)(base + (size_t)cc*8192);
      v[cc][0]+=p.x; v[cc][1]+=p.y; v[cc][2]+=p.z; v[cc][3]+=p.w;
    }
  }
  __syncthreads();
#pragma unroll
  for (int cc=0;cc<4;++cc)
#pragma unroll
    for (int k=0;k<4;++k)
      tr[(rq*4+k)*68 + cg*4+cc] = v[cc][k] * rinv[rq*4+k];
  __syncthreads();
  {
    int r = tid >> 2, q = tid & 3;
    int grow = r0 + r;
    if (grow < 8191) {
      float* dst = out + (size_t)grow*128 + c0 + q*16;
      const float* s2 = &tr[r*68 + q*16];
#pragma unroll
      for (int i=0;i<4;++i) *(float4*)(dst + i*4) = *(const float4*)(s2 + i*4);
    }
  }
}

extern "C" void kernel_launch(void* const* d_in, const int* in_sizes, int n_in,
                              void* d_out, int out_size, void* d_ws, size_t ws_size,
                              hipStream_t stream) {
  const float* X = (const float*)d_in[0];
  const float* y = (const float*)d_in[1];
  // d_in[2] = y_next (unused by reference)
  const float* R = (const float*)d_in[3];
  const float* t = (const float*)d_in[4];
  float* out = (float*)d_out;
  char* ws = (char*)d_ws;

  unsigned short* ctp = (unsigned short*)ws;                 // 128 * 32768 = 4 MB
  size_t ynoff = (size_t)128 * T_STRIDE;
  float* ynp = (float*)(ws + ynoff);                         // 32 KB
  size_t rspoff = ynoff + 32*1024;
  float* rsp  = (float*)(ws + rspoff);                       // js*32 KB
  size_t accoff = rspoff + 512*1024;
  float* accp = (float*)(ws + accoff);                       // js * 4 MB

  int js = 8;  // 64 x 8 = 512 blocks = exactly 2 blocks/CU (LDS 64 KB limit)
  while (js > 1 && accoff + (size_t)js*128*8192*4 > ws_size) js >>= 1;

  k_prep<<<dim3(192), dim3(256), 0, stream>>>(y, R, t, X, ctp, ynp);
  k_main<<<dim3(64, js), dim3(256), 0, stream>>>(X, ctp, ynp, accp, rsp, js);
  k_fin<<<dim3(128, 2), dim3(256), 0, stream>>>(accp, rsp, out, js);
}

// Round 7
// 139.727 us; speedup vs baseline: 1.2180x; 1.2180x over previous
//
#include <hip/hip_runtime.h>
#include <hip/hip_bf16.h>

// Gaussian-kernel regression, fused flash-attention style.
// 32-j tiles (16 KB), double-buffered LDS (2x16KB) + 17KB P-scratch = 50 KB
// -> 3 blocks/CU, ONE barrier per tile, prefetch issued right after barrier.
// S = (KA2C*yt)@x via 8 MFMA (two 4-deep chains), e = sa + yn (f32),
// g = exp2(e); P via per-wave LDS round-trip (stride 68, 2-way-free); PV 8 MFMA.
// K_prep: blocks 0..63: yt GEMM -> scaled perm + yn(f32); 64..191: V perm
// K_fin : reduce splits (col-split grid), normalize, transpose, store

#define LOG2E 1.44269504088896340736f
#define KNEG (-(1.0f/256.0f)*LOG2E)
#define KA2C (2.0f*(1.0f/256.0f)*LOG2E)

typedef __attribute__((ext_vector_type(4)))  float f32x4;
typedef __attribute__((ext_vector_type(16))) float f32x16;
typedef __attribute__((ext_vector_type(8)))  short bf16x8;

__device__ __forceinline__ unsigned short f2bf(float f) {
  unsigned u = __builtin_bit_cast(unsigned, f);
  u = (u + 0x7fffu + ((u >> 16) & 1u)) >> 16;  // RNE; inputs finite
  return (unsigned short)u;
}
__device__ __forceinline__ unsigned pk2bf(float a, float b) {
  __hip_bfloat162 h = __float22bfloat162_rn(float2{a, b});  // v_cvt_pk_bf16_f32
  unsigned u;
  __builtin_memcpy(&u, &h, 4);
  return u;
}
__device__ __forceinline__ bf16x8 pack8(float4 p0, float4 p1) {
  uint4 u;
  u.x = pk2bf(p0.x, p0.y); u.y = pk2bf(p0.z, p0.w);
  u.z = pk2bf(p1.x, p1.y); u.w = pk2bf(p1.z, p1.w);
  return __builtin_bit_cast(bf16x8, u);
}
__device__ __forceinline__ float fast_exp2(float x) {
#if __has_builtin(__builtin_amdgcn_exp2f)
  return __builtin_amdgcn_exp2f(x);
#else
  return exp2f(x);
#endif
}
__device__ __forceinline__ void gl2lds16(const void* g, void* l) {
  __builtin_amdgcn_global_load_lds((const __attribute__((address_space(1))) unsigned int*)g,
                                   (__attribute__((address_space(3))) unsigned int*)l, 16, 0, 0);
}
__device__ __forceinline__ f32x16 mfma_32x32x16(bf16x8 a, bf16x8 b, f32x16 c) {
  return __builtin_amdgcn_mfma_f32_32x32x16_bf16(a, b, c, 0, 0, 0);
}

#define T32S  16384   // per-32j-tile bytes: 8 yt chunks + 8 V chunks (1 KB each)
#define V32O  8192

// ---------------- K_prep ----------------
// blocks 0..63  : yt part, 128 rows/block (4 waves x 32 rows = 4 j-tiles)
// blocks 64..191: V part, 64 rows/block (2 j-tiles)
__global__ __launch_bounds__(256) void k_prep(const float* __restrict__ y,
                                              const float* __restrict__ R,
                                              const float* __restrict__ t,
                                              const float* __restrict__ X,
                                              unsigned short* __restrict__ ctp,
                                              float* __restrict__ ynp) {
  __shared__ union {
    unsigned short ytt[128 * 132];
    float xt[65 * 132];
  } sm;
  const int tid = threadIdx.x;

  if (blockIdx.x < 64) {
    // ------- yt = y@R^T + t; store KA2C*yt (bf16 perm) + yn (f32) -------
    const int wv = tid >> 6, ln = tid & 63;
    const int l = ln & 31, h = ln >> 5;
    const int B = blockIdx.x;
    const int rw = B * 128 + wv * 32;

    bf16x8 af[8];  // A-frag: y[rw+l][kc*16+8h+0..7]
    {
      int row = rw + l; if (row > 8190) row = 8190;
      const float* yr = y + (size_t)row * 128;
#pragma unroll
      for (int kc = 0; kc < 8; ++kc) {
        float4 p0 = *(const float4*)(yr + kc*16 + 8*h);
        float4 p1 = *(const float4*)(yr + kc*16 + 8*h + 4);
        af[kc] = pack8(p0, p1);
      }
    }
    f32x16 acc[4];
#pragma unroll
    for (int cc=0; cc<4; ++cc)
#pragma unroll
      for (int i=0;i<16;++i) acc[cc][i] = 0.f;
#pragma unroll
    for (int cc=0; cc<4; ++cc) {
      const float* Rr = R + (size_t)(cc*32 + l) * 128;  // B-frag: R^T[k][c] = R[c][k]
#pragma unroll
      for (int kc=0; kc<8; ++kc) {
        float4 p0 = *(const float4*)(Rr + kc*16 + 8*h);
        float4 p1 = *(const float4*)(Rr + kc*16 + 8*h + 4);
        acc[cc] = mfma_32x32x16(af[kc], pack8(p0, p1), acc[cc]);
      }
    }
    // D: lane holds yt[rw + (r&3)+8*(r>>2)+4h][cc*32 + l]
    float tv0 = t[l], tv1 = t[32+l], tv2 = t[64+l], tv3 = t[96+l];
    float v0[16], v1[16], v2[16], v3[16], ssq[16];
#pragma unroll
    for (int r=0;r<16;++r) {
      v0[r]=acc[0][r]+tv0; v1[r]=acc[1][r]+tv1; v2[r]=acc[2][r]+tv2; v3[r]=acc[3][r]+tv3;
      ssq[r] = v0[r]*v0[r] + v1[r]*v1[r] + v2[r]*v2[r] + v3[r]*v3[r];
    }
#pragma unroll
    for (int off=1; off<32; off<<=1)
#pragma unroll
      for (int r=0;r<16;++r) ssq[r] += __shfl_xor(ssq[r], off, 64);
    if (l < 16) {
      int r = l;
      int grow = rw + (r&3) + 8*(r>>2) + 4*h;
      ynp[grow] = (grow >= 8191) ? -1.0e30f : KNEG * ssq[r];  // pad j: g=0
    }
    // transpose scaled yt via LDS
#pragma unroll
    for (int r=0;r<16;++r) {
      int rloc = wv*32 + (r&3) + 8*(r>>2) + 4*h;
      sm.ytt[rloc*132 +   0 + l] = f2bf(KA2C * v0[r]);
      sm.ytt[rloc*132 +  32 + l] = f2bf(KA2C * v1[r]);
      sm.ytt[rloc*132 +  64 + l] = f2bf(KA2C * v2[r]);
      sm.ytt[rloc*132 +  96 + l] = f2bf(KA2C * v3[r]);
    }
    __syncthreads();
    // perm: [T32][kc(8)][lane(64)][8 bf16]; wave wv owns tile Tt = B*4+wv
    const int Tt = B*4 + wv;
    char* base = (char*)ctp + (size_t)Tt*T32S;
#pragma unroll
    for (int kc=0;kc<8;++kc) {
      const unsigned short* s = &sm.ytt[(wv*32 + l)*132 + kc*16 + 8*h];
      uint2 a = *(const uint2*)(s);
      uint2 b = *(const uint2*)(s + 4);
      uint4 o; o.x=a.x; o.y=a.y; o.z=b.x; o.w=b.y;
      *(uint4*)(base + kc*1024 + ln*16) = o;
    }
  } else {
    // ------- V = X[1:] transposed perm -------
    const int T = blockIdx.x - 64;
    const int jt = T * 64;
    {
      int rr = tid >> 2, q4 = tid & 3;
      int row = jt + rr; if (row > 8191) row = 8191;
      const float* src = X + (size_t)row*128 + q4*32;
      float* dst = &sm.xt[rr*132 + q4*32];
#pragma unroll
      for (int i=0;i<8;++i) *(float4*)(dst + i*4) = *(const float4*)(src + i*4);
      if (tid < 4) {
        int row2 = jt + 64; if (row2 > 8191) row2 = 8191;  // clamp (pad j has g=0)
        const float* s2 = X + (size_t)row2*128 + tid*32;
        float* d2 = &sm.xt[64*132 + tid*32];
#pragma unroll
        for (int i=0;i<8;++i) *(float4*)(d2 + i*4) = *(const float4*)(s2 + i*4);
      }
    }
    __syncthreads();
    // [T32][chunk = (jc16&1)*4+cc][lane][8 bf16]: lane -> X1[jc16*16+8h+i][cc*32+l]
#pragma unroll
    for (int it=0; it<4; ++it) {
      int E = tid + it*256;
      int lp = E & 63, grp = E >> 6;
      int cc = grp & 3, jc16 = grp >> 2;      // jc16 0..3 within 64 rows
      int jb = jc16*16 + 8*(lp>>5);
      int c  = cc*32 + (lp & 31);
      uint4 o;
      o.x = pk2bf(sm.xt[(jb+1)*132 + c], sm.xt[(jb+2)*132 + c]);
      o.y = pk2bf(sm.xt[(jb+3)*132 + c], sm.xt[(jb+4)*132 + c]);
      o.z = pk2bf(sm.xt[(jb+5)*132 + c], sm.xt[(jb+6)*132 + c]);
      o.w = pk2bf(sm.xt[(jb+7)*132 + c], sm.xt[(jb+8)*132 + c]);
      int t32 = T*2 + (jc16 >> 1);
      int chunk = (jc16 & 1)*4 + cc;
      *(uint4*)((char*)ctp + (size_t)t32*T32S + V32O + chunk*1024 + lp*16) = o;
    }
  }
}

// ---------------- K_main ----------------
// grid (64, js=12); block 256 = 4 waves x 32 query rows (BM=128); 3 blocks/CU.
// One barrier per 32-j tile; prefetch T+1 issued right after it.
__global__ __launch_bounds__(256, 3) void k_main(
    const float* __restrict__ X,
    const unsigned short* __restrict__ ctp,
    const float* __restrict__ ynp,
    float* __restrict__ accp,
    float* __restrict__ rsp,
    int js) {
  __shared__ unsigned short stg[2][T32S/2];    // 2 x 16 KB
  __shared__ unsigned short gls[4*32*68];      // per-wave P scratch (17 KB)
  const int tid = threadIdx.x;
  const int wv = tid >> 6, ln = tid & 63;
  const int l = ln & 31, h = ln >> 5;
  const int row = blockIdx.x*128 + wv*32 + l;  // query row, always < 8192

  bf16x8 qf[8];  // Q as B-operand: x[row][k = kc*16+8h+0..7]
  {
    const float* xr = X + (size_t)row * 128;
#pragma unroll
    for (int kc=0;kc<8;++kc) {
      float4 p0 = *(const float4*)(xr + kc*16 + 8*h);
      float4 p1 = *(const float4*)(xr + kc*16 + 8*h + 4);
      qf[kc] = pack8(p0, p1);
    }
  }
  f32x16 acc[4];
#pragma unroll
  for (int cc=0;cc<4;++cc)
#pragma unroll
    for (int i=0;i<16;++i) acc[cc][i]=0.f;
  float rs = 0.f;
  const int sp = blockIdx.y;
  const int Tbeg = (sp * 256) / js;
  const int Tend = ((sp + 1) * 256) / js;

  // stage first tile into buffer 0 (4 chunks per wave)
  {
    const char* cb = (const char*)ctp + (size_t)Tbeg*T32S;
#pragma unroll
    for (int i=0;i<4;++i) {
      int c = wv*4 + i;
      gl2lds16(cb + c*1024 + ln*16, (char*)stg[0] + c*1024);
    }
  }
  int cur = 0;
  for (int T = Tbeg; T < Tend; ++T) {
    __syncthreads();   // drains vmcnt -> stg[cur] ready; prior reads of stg[cur^1] done
    if (T + 1 < Tend) {
      const char* cb = (const char*)ctp + (size_t)(T+1)*T32S;
#pragma unroll
      for (int i=0;i<4;++i) {
        int c = wv*4 + i;
        gl2lds16(cb + c*1024 + ln*16, (char*)stg[cur^1] + c*1024);
      }
    }
    const char* yb = (const char*)stg[cur];
    const char* vb = (const char*)stg[cur] + V32O;
    // yn broadcast loads (L1-hot 32 KB array)
    f32x4 yv[4];
#pragma unroll
    for (int rg=0;rg<4;++rg)
      yv[rg] = *(const f32x4*)(ynp + T*32 + 8*rg + 4*h);
    // S: two independent 4-deep MFMA chains
    f32x16 s0, s1;
#pragma unroll
    for (int i=0;i<16;++i) { s0[i]=0.f; s1[i]=0.f; }
#pragma unroll
    for (int kc=0;kc<4;++kc) {
      bf16x8 a0 = *(const bf16x8*)(yb + (2*kc  )*1024 + ln*16);
      bf16x8 a1 = *(const bf16x8*)(yb + (2*kc+1)*1024 + ln*16);
      s0 = mfma_32x32x16(a0, qf[2*kc  ], s0);
      s1 = mfma_32x32x16(a1, qf[2*kc+1], s1);
    }
    // exp + P via per-wave LDS round-trip
    // lane holds e[j = i + 8*rg + 4h][m = l] at s[rg*4+i]
#pragma unroll
    for (int rg=0;rg<4;++rg) {
      float g0 = fast_exp2(s0[rg*4+0] + s1[rg*4+0] + yv[rg][0]);
      float g1 = fast_exp2(s0[rg*4+1] + s1[rg*4+1] + yv[rg][1]);
      float g2 = fast_exp2(s0[rg*4+2] + s1[rg*4+2] + yv[rg][2]);
      float g3 = fast_exp2(s0[rg*4+3] + s1[rg*4+3] + yv[rg][3]);
      rs += (g0+g1) + (g2+g3);
      uint2 w; w.x = pk2bf(g0, g1); w.y = pk2bf(g2, g3);
      int j0 = 8*rg + 4*h;
      *(uint2*)&gls[(wv*32+l)*68 + j0] = w;   // 8B-aligned b64 write, 2-way free
    }
    __builtin_amdgcn_wave_barrier();
#pragma unroll
    for (int jj=0; jj<2; ++jj) {          // local jc16
      const unsigned short* gp = &gls[(wv*32+l)*68 + jj*16 + 8*h];
      uint2 g0 = *(const uint2*)(gp);
      uint2 g1 = *(const uint2*)(gp + 4);
      uint4 gv; gv.x=g0.x; gv.y=g0.y; gv.z=g1.x; gv.w=g1.y;
      bf16x8 pb = __builtin_bit_cast(bf16x8, gv);
#pragma unroll
      for (int cc=0;cc<4;++cc) {
        bf16x8 a2 = *(const bf16x8*)(vb + (jj*4+cc)*1024 + ln*16);
        acc[cc] = mfma_32x32x16(a2, pb, acc[cc]);
      }
    }
    __builtin_amdgcn_wave_barrier();
    cur ^= 1;
  }
  rs += __shfl_xor(rs, 32, 64);
  if (h == 0) rsp[(size_t)sp*8192 + row] = rs;
  // acc^T: lane holds out^T[c = cc*32+(r&3)+8(r>>2)+4h][m = row]; store [sp][c][row]
#pragma unroll
  for (int cc=0;cc<4;++cc)
#pragma unroll
    for (int r=0;r<16;++r) {
      int c = cc*32 + (r&3) + 8*(r>>2) + 4*h;
      accp[((size_t)sp*128 + c)*8192 + row] = acc[cc][r];
    }
}

// ---------------- K_fin: col-split coalesced reduce + normalize + transpose ----------------
// grid (128, 2); block 256. Block: 64 rows x 64 cols.
__global__ __launch_bounds__(256) void k_fin(const float* __restrict__ accp,
                                             const float* __restrict__ rsp,
                                             float* __restrict__ out,
                                             int js) {
  __shared__ float tr[64*68];
  __shared__ float rinv[64];
  const int tid = threadIdx.x;
  const int r0 = blockIdx.x * 64;
  const int c0 = blockIdx.y * 64;
  if (tid < 64) {
    float s = 0.f;
    for (int sp=0; sp<js; ++sp) s += rsp[(size_t)sp*8192 + r0 + tid];
    rinv[tid] = 1.f / s;
  }
  const int rq = tid & 15, cg = tid >> 4;   // rows rq*4..+3, cols c0+cg*4..+3
  float v[4][4];
#pragma unroll
  for (int cc=0;cc<4;++cc)
#pragma unroll
    for (int k=0;k<4;++k) v[cc][k]=0.f;
  for (int sp=0; sp<js; ++sp) {
    const float* base = accp + ((size_t)sp*128 + c0 + cg*4)*8192 + r0 + rq*4;
#pragma unroll
    for (int cc=0; cc<4; ++cc) {
      float4 p = *(const float4*)(base + (size_t)cc*8192);
      v[cc][0]+=p.x; v[cc][1]+=p.y; v[cc][2]+=p.z; v[cc][3]+=p.w;
    }
  }
  __syncthreads();
#pragma unroll
  for (int cc=0;cc<4;++cc)
#pragma unroll
    for (int k=0;k<4;++k)
      tr[(rq*4+k)*68 + cg*4+cc] = v[cc][k] * rinv[rq*4+k];
  __syncthreads();
  {
    int r = tid >> 2, q = tid & 3;
    int grow = r0 + r;
    if (grow < 8191) {
      float* dst = out + (size_t)grow*128 + c0 + q*16;
      const float* s2 = &tr[r*68 + q*16];
#pragma unroll
      for (int i=0;i<4;++i) *(float4*)(dst + i*4) = *(const float4*)(s2 + i*4);
    }
  }
}

extern "C" void kernel_launch(void* const* d_in, const int* in_sizes, int n_in,
                              void* d_out, int out_size, void* d_ws, size_t ws_size,
                              hipStream_t stream) {
  const float* X = (const float*)d_in[0];
  const float* y = (const float*)d_in[1];
  // d_in[2] = y_next (unused by reference)
  const float* R = (const float*)d_in[3];
  const float* t = (const float*)d_in[4];
  float* out = (float*)d_out;
  char* ws = (char*)d_ws;

  unsigned short* ctp = (unsigned short*)ws;                 // 256 * 16384 = 4 MB
  size_t ynoff = (size_t)256 * T32S;
  float* ynp = (float*)(ws + ynoff);                         // 32 KB
  size_t rspoff = ynoff + 32*1024;
  float* rsp  = (float*)(ws + rspoff);                       // js*32 KB
  size_t accoff = rspoff + 512*1024;
  float* accp = (float*)(ws + accoff);                       // js * 4 MB

  int js = 12;  // 64 x 12 = 768 blocks = exactly 3 blocks/CU
  while (js > 1 && accoff + (size_t)js*128*8192*4 > ws_size) js >>= 1;

  k_prep<<<dim3(192), dim3(256), 0, stream>>>(y, R, t, X, ctp, ynp);
  k_main<<<dim3(64, js), dim3(256), 0, stream>>>(X, ctp, ynp, accp, rsp, js);
  k_fin<<<dim3(128, 2), dim3(256), 0, stream>>>(accp, rsp, out, js);
}